// Round 3
// baseline (391.132 us; speedup 1.0000x reference)
//
#include <hip/hip_runtime.h>
#include <hip/hip_bf16.h>
#include <hip/hip_cooperative_groups.h>
namespace cg = cooperative_groups;

// Problem constants (fixed by the reference)
#define ZBATCH 4
#define PN     512
#define CINC   32
#define COUTC  32
#define EN     65536
#define HIDN   128
#define NNODE  (ZBATCH*PN)     // 2048 nodes
#define JD     (HIDN*COUTC)    // 4096 = Wf elems per node
#define CAP    128             // per-node edge bin capacity (mean 32, max ~60)

// Single cooperative kernel: phases separated by grid.sync().
//  P0 zero counters | P1 bin edges by src+dst | P2 Wf[n][h][co]=W2.F[n]
//  P3 per-src-node msg[e][co]=H(e).Wf[src] | P4 per-dst-node reduce -> out
__global__ __launch_bounds__(256) void mega_k(
    const float* __restrict__ F, const float* __restrict__ evec,
    const float* __restrict__ W1, const float* __restrict__ b1,
    const float* __restrict__ W2, const int* __restrict__ eb,
    const int* __restrict__ ea, const int* __restrict__ ebn,
    const int* __restrict__ nn, float* __restrict__ out,
    __hip_bfloat16* __restrict__ Wf, float* __restrict__ msg,
    int* __restrict__ ints) {
  cg::grid_group grid = cg::this_grid();
  int* cnt_src   = ints;                    // NNODE
  int* cnt_dst   = ints + NNODE;            // NNODE
  int* order_src = ints + 2 * NNODE;        // NNODE*CAP
  int* order_dst = order_src + NNODE * CAP; // NNODE*CAP

  const int t = threadIdx.x, b = blockIdx.x, nblk = gridDim.x;
  const int gtid = b * 256 + t, gstr = nblk * 256;

  __shared__ float w1s[4][HIDN];
  __shared__ float b1s[HIDN];
  __shared__ __align__(16) float Hbuf[4][8][HIDN];   // wave-private 8-edge H

  // ---- P0: zero both counter arrays (ws is poisoned 0xAA each call) ----
  for (int i = gtid; i < 2 * NNODE; i += gstr) cnt_src[i] = 0;
  grid.sync();

  // ---- P1: bin edges into fixed-capacity src and dst bins ----
  for (int e = gtid; e < EN; e += gstr) {
    const int zb = eb[e];
    const int ns = zb * PN + ebn[e];
    const int nd = zb * PN + ea[e];
    const int p = atomicAdd(&cnt_src[ns], 1);
    if (p < CAP) order_src[ns * CAP + p] = e;
    const int q = atomicAdd(&cnt_dst[nd], 1);
    if (q < CAP) order_dst[nd * CAP + q] = e;
  }
  // stage MLP weights for P3 while others bin
  for (int i = t; i < 4 * HIDN; i += 256) w1s[i >> 7][i & 127] = W1[i];
  for (int i = t; i < HIDN; i += 256) b1s[i] = b1[i];
  grid.sync();

  // ---- P2: Wf[n][h][co] = sum_ci W2[h][co*32+ci] * F[n][ci] (bf16 store) ----
  for (int u = b; u < 2048; u += nblk) {
    const int j = (u & 15) * 256 + t;     // 0..4095 = (h,co)
    const int n0 = (u >> 4) * 16;
    const int h = j >> 5, co = j & 31;
    const float4* w4 = (const float4*)(W2 + h * (COUTC * CINC) + co * CINC);
    float w[32];
#pragma unroll
    for (int q = 0; q < 8; ++q) {
      const float4 x = w4[q];
      w[4 * q] = x.x; w[4 * q + 1] = x.y; w[4 * q + 2] = x.z; w[4 * q + 3] = x.w;
    }
    for (int n = 0; n < 16; ++n) {
      const float* fr = F + (size_t)(n0 + n) * CINC;  // wave-uniform address
      float acc = 0.f;
#pragma unroll
      for (int ci = 0; ci < 32; ++ci) acc = fmaf(fr[ci], w[ci], acc);
      Wf[(size_t)(n0 + n) * JD + j] = __float2bfloat16(acc);
    }
  }
  grid.sync();

  // ---- P3: per src node: H per edge -> msg[e][co] (no atomics) ----
  const int lane = t & 63, w = t >> 6;
  const int co = lane & 31, hh = lane >> 5;
  const float scale = rsqrtf((float)nn[0]);
  const int h0 = lane << 1;
  for (int n = b; n < NNODE; n += nblk) {
    const int c0 = cnt_src[n];
    const int count = c0 < CAP ? c0 : CAP;     // block-uniform
    if (count == 0) continue;
    float wf[64];
    {
      const __hip_bfloat16* wp = Wf + (size_t)n * JD + hh * 64 * COUTC + co;
#pragma unroll
      for (int j = 0; j < 64; ++j) wf[j] = __bfloat162float(wp[(size_t)j * COUTC]);
    }
    const int* ord = order_src + (size_t)n * CAP;
    for (int base = w * 8; base < count; base += 32) {
      const int nb = (count - base < 8) ? (count - base) : 8;
      for (int i = 0; i < nb; ++i) {        // H: lane computes h-pair per edge
        const int e = ord[base + i];
        const float x0 = evec[3 * e], x1 = evec[3 * e + 1], x2 = evec[3 * e + 2];
        const float r = sqrtf(x0 * x0 + x1 * x1 + x2 * x2);
        const bool bad = (r < 1e-10f);
        const float y0 = bad ? 0.f : x0, y1 = bad ? 0.f : x1;
        const float y2 = bad ? 0.f : x2, y3 = bad ? 0.f : r;
        float a0 = b1s[h0]     + y0 * w1s[0][h0]     + y1 * w1s[1][h0]
                               + y2 * w1s[2][h0]     + y3 * w1s[3][h0];
        float a1 = b1s[h0 + 1] + y0 * w1s[0][h0 + 1] + y1 * w1s[1][h0 + 1]
                               + y2 * w1s[2][h0 + 1] + y3 * w1s[3][h0 + 1];
        float2 hv;
        hv.x = fmaxf(a0, 0.f);
        hv.y = fmaxf(a1, 0.f);
        *(float2*)(&Hbuf[w][i][h0]) = hv;
      }
      __builtin_amdgcn_wave_barrier();      // wave-synchronous LDS (DS in-order)
      for (int i = 0; i < nb; ++i) {        // msg: dot(H[e][hh half], wf)
        const int e = ord[base + i];
        const float* hp = &Hbuf[w][i][hh * 64];
        float acc = 0.f;
#pragma unroll
        for (int k = 0; k < 16; ++k) {
          const float4 h4 = *(const float4*)(hp + 4 * k);
          acc = fmaf(h4.x, wf[4 * k],     acc);
          acc = fmaf(h4.y, wf[4 * k + 1], acc);
          acc = fmaf(h4.z, wf[4 * k + 2], acc);
          acc = fmaf(h4.w, wf[4 * k + 3], acc);
        }
        acc += __shfl_xor(acc, 32);         // combine the two h-halves
        if (hh == 0) msg[(size_t)e * COUTC + co] = acc * scale;
      }
      __builtin_amdgcn_wave_barrier();
    }
  }
  grid.sync();

  // ---- P4: per dst node: out[n][co] = sum over its edges of msg[e][co] ----
  for (int n = b * 4 + w; n < NNODE; n += nblk * 4) {
    const int c0 = cnt_dst[n];
    const int count = c0 < CAP ? c0 : CAP;
    float acc = 0.f;
    for (int i = hh; i < count; i += 2)
      acc += msg[(size_t)order_dst[(size_t)n * CAP + i] * COUTC + co];
    acc += __shfl_xor(acc, 32);
    if (hh == 0) out[(size_t)n * COUTC + co] = acc;  // every out elem written
  }
}

extern "C" void kernel_launch(void* const* d_in, const int* in_sizes, int n_in,
                              void* d_out, int out_size, void* d_ws, size_t ws_size,
                              hipStream_t stream) {
  const float* features   = (const float*)d_in[0];
  const float* edge_vec   = (const float*)d_in[1];
  const float* W1         = (const float*)d_in[2];
  const float* b1         = (const float*)d_in[3];
  const float* W2         = (const float*)d_in[4];
  const int*   edge_batch = (const int*)d_in[5];
  const int*   edge_a     = (const int*)d_in[6];
  const int*   edge_b     = (const int*)d_in[7];
  const int*   n_norm     = (const int*)d_in[8];
  float* out = (float*)d_out;

  char* ws = (char*)d_ws;
  __hip_bfloat16* Wf = (__hip_bfloat16*)ws;                    // 16 MiB
  float* msg = (float*)(ws + (size_t)NNODE * JD * 2);          // 8 MiB
  int* ints = (int*)(ws + (size_t)NNODE * JD * 2 + (size_t)EN * COUTC * 4);
  const size_t need = (size_t)NNODE * JD * 2 + (size_t)EN * COUTC * 4
                    + (size_t)(2 * NNODE + 2 * NNODE * CAP) * 4;
  if (ws_size < need) return;

  int nblk = 512;                       // 2 blocks/CU target
  int maxb = 0;
  if (hipOccupancyMaxActiveBlocksPerMultiprocessor(&maxb, mega_k, 256, 0)
          == hipSuccess && maxb > 0) {
    const int cap = maxb * 256;         // 256 CUs on MI355X
    if (cap < nblk) nblk = cap;
  }
  void* args[] = {
    (void*)&features, (void*)&edge_vec, (void*)&W1, (void*)&b1, (void*)&W2,
    (void*)&edge_batch, (void*)&edge_a, (void*)&edge_b, (void*)&n_norm,
    (void*)&out, (void*)&Wf, (void*)&msg, (void*)&ints
  };
  hipLaunchCooperativeKernel((void*)mega_k, dim3(nblk), dim3(256), args, 0,
                             stream);
}

// Round 6
// 144.584 us; speedup vs baseline: 2.7052x; 2.7052x over previous
//
#include <hip/hip_runtime.h>
#include <hip/hip_bf16.h>

// Problem constants (fixed by the reference)
#define ZBATCH 4
#define PN     512
#define CINC   32
#define COUTC  32
#define EN     65536
#define HIDN   128
#define NNODE  (ZBATCH*PN)     // 2048 nodes
#define JD     (HIDN*COUTC)    // 4096 = Wf elems per node
#define CAP    128             // per-node edge bin cap (mean 32, max ~60)

// ---- K1: block-role split. Blocks [0,256): bin edges by src+dst.
//      Blocks [256,2304): Wf[n][h][co] = sum_ci W2[h][co*32+ci]*F[n][ci]. ----
__global__ __launch_bounds__(256) void k1_bin_wf(
    const float* __restrict__ F, const float* __restrict__ W2,
    __hip_bfloat16* __restrict__ Wf, const int* __restrict__ eb,
    const int* __restrict__ ea, const int* __restrict__ ebn,
    int* __restrict__ cnt_src, int* __restrict__ cnt_dst,
    int* __restrict__ order_src, int* __restrict__ order_dst) {
  const int t = threadIdx.x;
  const int b = blockIdx.x;
  if (b < 256) {                       // ---- bin role ----
    const int e = b * 256 + t;
    const int zb = eb[e];
    const int ns = zb * PN + ebn[e];
    const int nd = zb * PN + ea[e];
    const int p = atomicAdd(&cnt_src[ns], 1);
    if (p < CAP) order_src[ns * CAP + p] = e;
    const int q = atomicAdd(&cnt_dst[nd], 1);
    if (q < CAP) order_dst[nd * CAP + q] = e;
    return;
  }
  // ---- Wf role ----
  const int bb = b - 256;
  const int j = (bb & 15) * 256 + t;   // 0..4095 = (h,co)
  const int n0 = (bb >> 4) * 16;
  const int h = j >> 5, co = j & 31;
  const float4* w4 = (const float4*)(W2 + h * (COUTC * CINC) + co * CINC);
  float w[32];
#pragma unroll
  for (int q = 0; q < 8; ++q) {
    const float4 x = w4[q];
    w[4 * q] = x.x; w[4 * q + 1] = x.y; w[4 * q + 2] = x.z; w[4 * q + 3] = x.w;
  }
  for (int n = 0; n < 16; ++n) {
    const float* fr = F + (size_t)(n0 + n) * CINC;   // wave-uniform address
    float acc = 0.f;
#pragma unroll
    for (int ci = 0; ci < 32; ++ci) acc = fmaf(fr[ci], w[ci], acc);
    Wf[(size_t)(n0 + n) * JD + j] = __float2bfloat16(acc);
  }
}

// ---- K2: per src node, msg[e][co] = H(e) . Wf[n][:][co]. Fully unrolled
//      8-edge batches (clamped idx + masked store): no dynamic inner loops. ----
__global__ __launch_bounds__(256) void k2_msg(
    const float* __restrict__ evec, const float* __restrict__ W1,
    const float* __restrict__ b1, const __hip_bfloat16* __restrict__ Wf,
    const int* __restrict__ cnt_src, const int* __restrict__ order_src,
    const int* __restrict__ nn, float* __restrict__ msg) {
  const int n = blockIdx.x;
  const int t = threadIdx.x;
  const int lane = t & 63, w = t >> 6;
  const int co = lane & 31, hh = lane >> 5;

  __shared__ float w1s[4][HIDN];
  __shared__ float b1s[HIDN];
  __shared__ int ords[CAP];
  __shared__ __align__(16) float Hbuf[4][8][HIDN];

  const int c0 = cnt_src[n];
  const int count = c0 < CAP ? c0 : CAP;     // block-uniform
  if (count == 0) return;

  for (int i = t; i < 4 * HIDN; i += 256) w1s[i >> 7][i & 127] = W1[i];
  for (int i = t; i < HIDN; i += 256) b1s[i] = b1[i];
  if (t < count) ords[t] = order_src[(size_t)n * CAP + t];   // count<=128

  float wf[64];
  {
    const __hip_bfloat16* wp = Wf + (size_t)n * JD + hh * 64 * COUTC + co;
#pragma unroll
    for (int j = 0; j < 64; ++j) wf[j] = __bfloat162float(wp[(size_t)j * COUTC]);
  }
  const float scale = rsqrtf((float)nn[0]);
  __syncthreads();                            // ords/w1s/b1s visible

  const int h0 = lane << 1;
  for (int base = w * 8; base < count; base += 32) {
    // -- prefetch 8 edge ids + vectors (clamped; all loads issue together) --
    int e8[8]; float ex[8], ey[8], ez[8];
#pragma unroll
    for (int i = 0; i < 8; ++i) {
      const int idx = (base + i < count) ? (base + i) : (count - 1);
      e8[i] = ords[idx];
    }
#pragma unroll
    for (int i = 0; i < 8; ++i) {
      ex[i] = evec[3 * e8[i]];
      ey[i] = evec[3 * e8[i] + 1];
      ez[i] = evec[3 * e8[i] + 2];
    }
    // -- H phase: lane computes h-pair (2*lane, 2*lane+1), 8 edges unrolled --
#pragma unroll
    for (int i = 0; i < 8; ++i) {
      const float r = sqrtf(ex[i] * ex[i] + ey[i] * ey[i] + ez[i] * ez[i]);
      const bool bad = (r < 1e-10f);
      const float y0 = bad ? 0.f : ex[i], y1 = bad ? 0.f : ey[i];
      const float y2 = bad ? 0.f : ez[i], y3 = bad ? 0.f : r;
      float a0 = b1s[h0]     + y0 * w1s[0][h0]     + y1 * w1s[1][h0]
                             + y2 * w1s[2][h0]     + y3 * w1s[3][h0];
      float a1 = b1s[h0 + 1] + y0 * w1s[0][h0 + 1] + y1 * w1s[1][h0 + 1]
                             + y2 * w1s[2][h0 + 1] + y3 * w1s[3][h0 + 1];
      float2 hv;
      hv.x = fmaxf(a0, 0.f);
      hv.y = fmaxf(a1, 0.f);
      *(float2*)(&Hbuf[w][i][h0]) = hv;
    }
    __builtin_amdgcn_wave_barrier();          // wave-private LDS, DS in-order
    // -- msg phase: 8 edges unrolled, 4 independent accumulator chains --
#pragma unroll
    for (int i = 0; i < 8; ++i) {
      const float4* hp = (const float4*)(&Hbuf[w][i][hh * 64]);
      float a0 = 0.f, a1 = 0.f, a2 = 0.f, a3 = 0.f;
#pragma unroll
      for (int k = 0; k < 4; ++k) {
        const float4 p0 = hp[4 * k + 0];
        const float4 p1 = hp[4 * k + 1];
        const float4 p2 = hp[4 * k + 2];
        const float4 p3 = hp[4 * k + 3];
        a0 = fmaf(p0.x, wf[16 * k + 0], a0);  a0 = fmaf(p0.y, wf[16 * k + 1], a0);
        a0 = fmaf(p0.z, wf[16 * k + 2], a0);  a0 = fmaf(p0.w, wf[16 * k + 3], a0);
        a1 = fmaf(p1.x, wf[16 * k + 4], a1);  a1 = fmaf(p1.y, wf[16 * k + 5], a1);
        a1 = fmaf(p1.z, wf[16 * k + 6], a1);  a1 = fmaf(p1.w, wf[16 * k + 7], a1);
        a2 = fmaf(p2.x, wf[16 * k + 8], a2);  a2 = fmaf(p2.y, wf[16 * k + 9], a2);
        a2 = fmaf(p2.z, wf[16 * k + 10], a2); a2 = fmaf(p2.w, wf[16 * k + 11], a2);
        a3 = fmaf(p3.x, wf[16 * k + 12], a3); a3 = fmaf(p3.y, wf[16 * k + 13], a3);
        a3 = fmaf(p3.z, wf[16 * k + 14], a3); a3 = fmaf(p3.w, wf[16 * k + 15], a3);
      }
      float acc = (a0 + a1) + (a2 + a3);
      acc += __shfl_xor(acc, 32);             // combine the two h-halves
      if (hh == 0 && base + i < count)
        msg[(size_t)e8[i] * COUTC + co] = acc * scale;
    }
    __builtin_amdgcn_wave_barrier();
  }
}

// ---- K3: per dst node (1 wave each), out[n][co] = sum_e msg[e][co] ----
__global__ __launch_bounds__(256) void k3_reduce(
    const float* __restrict__ msg, const int* __restrict__ cnt_dst,
    const int* __restrict__ order_dst, float* __restrict__ out) {
  const int t = threadIdx.x;
  const int lane = t & 63, w = t >> 6;
  const int co = lane & 31, hh = lane >> 5;
  const int n = blockIdx.x * 4 + w;
  __shared__ int idxs[4][CAP];
  const int c0 = cnt_dst[n];
  const int count = c0 < CAP ? c0 : CAP;
  for (int i = lane; i < count; i += 64)
    idxs[w][i] = order_dst[(size_t)n * CAP + i];
  __builtin_amdgcn_wave_barrier();            // wave-private LDS slice
  float a0 = 0.f, a1 = 0.f, a2 = 0.f, a3 = 0.f;
  for (int g = hh * 4; g < count; g += 8) {   // 4 loads in flight per half-wave
    const int i1 = g + 1, i2 = g + 2, i3 = g + 3;
    a0 += msg[(size_t)idxs[w][g] * COUTC + co];
    if (i1 < count) a1 += msg[(size_t)idxs[w][i1] * COUTC + co];
    if (i2 < count) a2 += msg[(size_t)idxs[w][i2] * COUTC + co];
    if (i3 < count) a3 += msg[(size_t)idxs[w][i3] * COUTC + co];
  }
  float acc = (a0 + a1) + (a2 + a3);
  acc += __shfl_xor(acc, 32);
  if (hh == 0) out[(size_t)n * COUTC + co] = acc;   // all out elems written
}

extern "C" void kernel_launch(void* const* d_in, const int* in_sizes, int n_in,
                              void* d_out, int out_size, void* d_ws, size_t ws_size,
                              hipStream_t stream) {
  const float* features   = (const float*)d_in[0];
  const float* edge_vec   = (const float*)d_in[1];
  const float* W1         = (const float*)d_in[2];
  const float* b1         = (const float*)d_in[3];
  const float* W2         = (const float*)d_in[4];
  const int*   edge_batch = (const int*)d_in[5];
  const int*   edge_a     = (const int*)d_in[6];
  const int*   edge_b     = (const int*)d_in[7];
  const int*   n_norm     = (const int*)d_in[8];
  float* out = (float*)d_out;

  char* ws = (char*)d_ws;
  __hip_bfloat16* Wf = (__hip_bfloat16*)ws;                    // 16 MiB
  float* msg = (float*)(ws + (size_t)NNODE * JD * 2);          // 8 MiB
  int* ints = (int*)(ws + (size_t)NNODE * JD * 2 + (size_t)EN * COUTC * 4);
  int* cnt_src   = ints;                        // NNODE
  int* cnt_dst   = ints + NNODE;                // NNODE
  int* order_src = ints + 2 * NNODE;            // NNODE*CAP
  int* order_dst = order_src + NNODE * CAP;     // NNODE*CAP
  const size_t need = (size_t)NNODE * JD * 2 + (size_t)EN * COUTC * 4
                    + (size_t)(2 * NNODE + 2 * NNODE * CAP) * 4;
  if (ws_size < need) return;

  hipMemsetAsync(cnt_src, 0, 2 * NNODE * 4, stream);
  k1_bin_wf<<<256 + 2048, 256, 0, stream>>>(features, W2, Wf, edge_batch,
                                            edge_a, edge_b, cnt_src, cnt_dst,
                                            order_src, order_dst);
  k2_msg<<<NNODE, 256, 0, stream>>>(edge_vec, W1, b1, Wf, cnt_src, order_src,
                                    n_norm, msg);
  k3_reduce<<<NNODE / 4, 256, 0, stream>>>(msg, cnt_dst, order_dst, out);
}

// Round 8
// 141.076 us; speedup vs baseline: 2.7725x; 1.0249x over previous
//
#include <hip/hip_runtime.h>

// Problem constants (fixed by the reference)
#define ZBATCH 4
#define PN     512
#define CINC   32
#define COUTC  32
#define EN     65536
#define HIDN   128
#define NNODE  (ZBATCH*PN)   // 2048 nodes
#define CAP    128           // per-node edge bin cap (mean 32, +17 sigma)
#define HP     64            // h-pairs (128 h / 2)
#define WFW    (HP*COUTC)    // 2048 u32 words per node (f16x2 each)

// Use the builtin's own half-vector type to avoid __fp16/_Float16 clashes.
using hvec2 = decltype(__builtin_amdgcn_cvt_pkrtz(0.f, 0.f));

static __device__ __forceinline__ unsigned packh2(float a, float b) {
  hvec2 h = __builtin_amdgcn_cvt_pkrtz(a, b);   // v_cvt_pkrtz_f16_f32
  unsigned u;
  __builtin_memcpy(&u, &h, 4);
  return u;
}

static __device__ __forceinline__ float dot2acc(unsigned hu, unsigned wu,
                                                float acc) {
  hvec2 a, b;
  __builtin_memcpy(&a, &hu, 4);
  __builtin_memcpy(&b, &wu, 4);
#if __has_builtin(__builtin_amdgcn_fdot2)
  return __builtin_amdgcn_fdot2(a, b, acc, false);   // v_dot2_f32_f16
#else
  acc = fmaf((float)a.x, (float)b.x, acc);
  return fmaf((float)a.y, (float)b.y, acc);
#endif
}

// ---- K1: blocks [0,256): bin edges by src+dst.
//      blocks [256,768): Wf f16-pair, layout [node][co][hp]:
//      word(n,co,hp)=(Wf[2hp][co],Wf[2hp+1][co]), Wf[h][co]=sum_ci W2[h][co*32+ci]*F[n][ci]
__global__ __launch_bounds__(256) void k1_bin_wf(
    const float* __restrict__ F, const float* __restrict__ W2,
    unsigned* __restrict__ Wf, const int* __restrict__ eb,
    const int* __restrict__ ea, const int* __restrict__ ebn,
    int* __restrict__ cnt_src, int* __restrict__ cnt_dst,
    int* __restrict__ order_src, int* __restrict__ order_dst) {
  const int t = threadIdx.x;
  const int b = blockIdx.x;
  if (b < 256) {                       // ---- bin role ----
    const int e = b * 256 + t;
    const int zb = eb[e];
    const int ns = zb * PN + ebn[e];
    const int nd = zb * PN + ea[e];
    const int p = atomicAdd(&cnt_src[ns], 1);
    if (p < CAP) order_src[ns * CAP + p] = e;
    const int q = atomicAdd(&cnt_dst[nd], 1);
    if (q < CAP) order_dst[nd * CAP + q] = e;
    return;
  }
  // ---- Wf role: thread = (hp, co-slice); 32 nodes per block ----
  const int bb = b - 256;              // 0..511
  const int jt = bb & 7, ntile = bb >> 3;
  const int hp = t & 63;               // h-pair index 0..63
  const int co = jt * 4 + (t >> 6);    // 0..31
  const float4* rA = (const float4*)(W2 + (size_t)(2 * hp) * (COUTC * CINC)
                                     + co * CINC);
  const float4* rB = (const float4*)(W2 + (size_t)(2 * hp + 1) * (COUTC * CINC)
                                     + co * CINC);
  float4 wa[8], wb[8];
#pragma unroll
  for (int q = 0; q < 8; ++q) { wa[q] = rA[q]; wb[q] = rB[q]; }
  const int n0 = ntile * 32;
  for (int n = 0; n < 32; ++n) {
    const float4* fr = (const float4*)(F + (size_t)(n0 + n) * CINC); // uniform
    float a0 = 0.f, a1 = 0.f, a2 = 0.f, a3 = 0.f;
    float c0 = 0.f, c1 = 0.f, c2 = 0.f, c3 = 0.f;
#pragma unroll
    for (int q = 0; q < 8; ++q) {
      const float4 f = fr[q];
      a0 = fmaf(f.x, wa[q].x, a0); a1 = fmaf(f.y, wa[q].y, a1);
      a2 = fmaf(f.z, wa[q].z, a2); a3 = fmaf(f.w, wa[q].w, a3);
      c0 = fmaf(f.x, wb[q].x, c0); c1 = fmaf(f.y, wb[q].y, c1);
      c2 = fmaf(f.z, wb[q].z, c2); c3 = fmaf(f.w, wb[q].w, c3);
    }
    Wf[(size_t)(n0 + n) * WFW + co * HP + hp] =
        packh2((a0 + a1) + (a2 + a3), (c0 + c1) + (c2 + c3));
  }
}

// ---- K2: per src node, msg[e][co] = H(e).Wf[n][:][co] via f16 dot2.
//      Lane=(co,hh); wf words in regs (8 coalesced uint4); H packed f16x2
//      into LDS (1 ds_write_b32/edge); dot = 8 uint4 LDS reads + 32 dot2. ----
__global__ __launch_bounds__(256) void k2_msg(
    const float* __restrict__ evec, const float* __restrict__ W1,
    const float* __restrict__ b1, const unsigned* __restrict__ Wf,
    const int* __restrict__ cnt_src, const int* __restrict__ order_src,
    const int* __restrict__ nn, float* __restrict__ msg) {
  const int n = blockIdx.x;
  const int t = threadIdx.x;
  const int lane = t & 63, w = t >> 6;
  const int co = lane & 31, hh = lane >> 5;

  __shared__ int ords[CAP];
  __shared__ __align__(16) unsigned Hbuf[4][8][64];   // [wave][edge][h-pair]

  const int c0 = cnt_src[n];
  const int count = c0 < CAP ? c0 : CAP;       // block-uniform
  if (count == 0) return;

  uint4 wfv[8];                                 // this lane's 32 wf words
  {
    const uint4* wp = (const uint4*)(Wf + (size_t)n * WFW + co * HP + hh * 32);
#pragma unroll
    for (int q = 0; q < 8; ++q) wfv[q] = wp[q];
  }
  if (t < count) ords[t] = order_src[(size_t)n * CAP + t];
  // W1 rows for this lane's h-pair (h0=2*lane, h0+1) straight from global (L2)
  const int h0 = lane << 1;
  const float2 u0 = *(const float2*)(W1 + 0 * HIDN + h0);
  const float2 u1 = *(const float2*)(W1 + 1 * HIDN + h0);
  const float2 u2 = *(const float2*)(W1 + 2 * HIDN + h0);
  const float2 u3 = *(const float2*)(W1 + 3 * HIDN + h0);
  const float2 b2 = *(const float2*)(b1 + h0);
  const float scale = rsqrtf((float)nn[0]);
  __syncthreads();                              // ords visible

  for (int base = w * 8; base < count; base += 32) {
    int e8[8]; float ex[8], ey[8], ez[8];
#pragma unroll
    for (int i = 0; i < 8; ++i) {
      const int idx = (base + i < count) ? (base + i) : (count - 1);
      e8[i] = ords[idx];
    }
#pragma unroll
    for (int i = 0; i < 8; ++i) {
      ex[i] = evec[3 * e8[i]];
      ey[i] = evec[3 * e8[i] + 1];
      ez[i] = evec[3 * e8[i] + 2];
    }
    // -- H phase: lane computes h-pair, packs f16x2, 1 ds_write per edge --
#pragma unroll
    for (int i = 0; i < 8; ++i) {
      const float r = sqrtf(ex[i] * ex[i] + ey[i] * ey[i] + ez[i] * ez[i]);
      const bool bad = (r < 1e-10f);
      const float y0 = bad ? 0.f : ex[i], y1 = bad ? 0.f : ey[i];
      const float y2 = bad ? 0.f : ez[i], y3 = bad ? 0.f : r;
      const float a0 = fmaf(y3, u3.x, fmaf(y2, u2.x,
                       fmaf(y1, u1.x, fmaf(y0, u0.x, b2.x))));
      const float a1 = fmaf(y3, u3.y, fmaf(y2, u2.y,
                       fmaf(y1, u1.y, fmaf(y0, u0.y, b2.y))));
      Hbuf[w][i][lane] = packh2(fmaxf(a0, 0.f), fmaxf(a1, 0.f));
    }
    __builtin_amdgcn_wave_barrier();            // wave-private LDS, DS in-order
    // -- msg phase: 8 uint4 LDS reads + 32 dot2 per edge, 4 acc chains --
#pragma unroll
    for (int i = 0; i < 8; ++i) {
      const uint4* hp4 = (const uint4*)&Hbuf[w][i][hh * 32];
      float s0 = 0.f, s1 = 0.f, s2 = 0.f, s3 = 0.f;
#pragma unroll
      for (int q = 0; q < 8; ++q) {
        const uint4 hv = hp4[q];
        s0 = dot2acc(hv.x, wfv[q].x, s0);
        s1 = dot2acc(hv.y, wfv[q].y, s1);
        s2 = dot2acc(hv.z, wfv[q].z, s2);
        s3 = dot2acc(hv.w, wfv[q].w, s3);
      }
      float acc = (s0 + s1) + (s2 + s3);
      acc += __shfl_xor(acc, 32);               // combine the two hh halves
      if (hh == 0 && base + i < count)
        msg[(size_t)e8[i] * COUTC + co] = acc * scale;
    }
    __builtin_amdgcn_wave_barrier();
  }
}

// ---- K3: per dst node (1 wave each), out[n][co] = sum_e msg[e][co] ----
__global__ __launch_bounds__(256) void k3_reduce(
    const float* __restrict__ msg, const int* __restrict__ cnt_dst,
    const int* __restrict__ order_dst, float* __restrict__ out) {
  const int t = threadIdx.x;
  const int lane = t & 63, w = t >> 6;
  const int co = lane & 31, hh = lane >> 5;
  const int n = blockIdx.x * 4 + w;
  __shared__ int idxs[4][CAP];
  const int c0 = cnt_dst[n];
  const int count = c0 < CAP ? c0 : CAP;
  for (int i = lane; i < count; i += 64)
    idxs[w][i] = order_dst[(size_t)n * CAP + i];
  __builtin_amdgcn_wave_barrier();              // wave-private LDS slice
  float a0 = 0.f, a1 = 0.f, a2 = 0.f, a3 = 0.f;
  for (int g = hh * 4; g < count; g += 8) {     // 4 loads in flight per half
    const int i1 = g + 1, i2 = g + 2, i3 = g + 3;
    a0 += msg[(size_t)idxs[w][g] * COUTC + co];
    if (i1 < count) a1 += msg[(size_t)idxs[w][i1] * COUTC + co];
    if (i2 < count) a2 += msg[(size_t)idxs[w][i2] * COUTC + co];
    if (i3 < count) a3 += msg[(size_t)idxs[w][i3] * COUTC + co];
  }
  float acc = (a0 + a1) + (a2 + a3);
  acc += __shfl_xor(acc, 32);
  if (hh == 0) out[(size_t)n * COUTC + co] = acc;   // all out elems written
}

extern "C" void kernel_launch(void* const* d_in, const int* in_sizes, int n_in,
                              void* d_out, int out_size, void* d_ws, size_t ws_size,
                              hipStream_t stream) {
  const float* features   = (const float*)d_in[0];
  const float* edge_vec   = (const float*)d_in[1];
  const float* W1         = (const float*)d_in[2];
  const float* b1         = (const float*)d_in[3];
  const float* W2         = (const float*)d_in[4];
  const int*   edge_batch = (const int*)d_in[5];
  const int*   edge_a     = (const int*)d_in[6];
  const int*   edge_b     = (const int*)d_in[7];
  const int*   n_norm     = (const int*)d_in[8];
  float* out = (float*)d_out;

  char* ws = (char*)d_ws;
  unsigned* Wf = (unsigned*)ws;                                // 2048*2048 u32 = 16 MiB
  float* msg = (float*)(ws + (size_t)NNODE * WFW * 4);         // 8 MiB
  int* ints = (int*)(ws + (size_t)NNODE * WFW * 4 + (size_t)EN * COUTC * 4);
  int* cnt_src   = ints;                        // NNODE
  int* cnt_dst   = ints + NNODE;                // NNODE
  int* order_src = ints + 2 * NNODE;            // NNODE*CAP
  int* order_dst = order_src + NNODE * CAP;     // NNODE*CAP
  const size_t need = (size_t)NNODE * WFW * 4 + (size_t)EN * COUTC * 4
                    + (size_t)(2 * NNODE + 2 * NNODE * CAP) * 4;
  if (ws_size < need) return;

  (void)hipMemsetAsync(cnt_src, 0, 2 * NNODE * 4, stream);
  k1_bin_wf<<<256 + 512, 256, 0, stream>>>(features, W2, Wf, edge_batch,
                                           edge_a, edge_b, cnt_src, cnt_dst,
                                           order_src, order_dst);
  k2_msg<<<NNODE, 256, 0, stream>>>(edge_vec, W1, b1, Wf, cnt_src, order_src,
                                    n_norm, msg);
  k3_reduce<<<NNODE / 4, 256, 0, stream>>>(msg, cnt_dst, order_dst, out);
}